// Round 6
// baseline (353.543 us; speedup 1.0000x reference)
//
#include <hip/hip_runtime.h>

#define B  8
#define N  8192
#define M  2048
#define C  64
#define CT 64
#define K  32
#define R2 0.04f   // nearest f32 to 0.2*0.2, matches jnp/np promotion

__device__ __forceinline__ float rfl(float x) {
    union { float f; int i; } u;
    u.f = x;
    u.i = __builtin_amdgcn_readfirstlane(u.i);
    return u.f;
}

// ---------------------------------------------------------------------------
// Kernel 0: transpose feats/temb [B,64,N] -> [B,N,64]; points [B,3,N] ->
// [B,N,4] with .w = px^2+py^2+pz^2 (exact np op order, reused by ball query).
// ---------------------------------------------------------------------------
__global__ __launch_bounds__(256) void transpose_kernel(
    const float* __restrict__ points,   // [B,3,N]
    const float* __restrict__ temb,     // [B,CT,N]
    const float* __restrict__ feats,    // [B,C,N]
    float* __restrict__ pointsT,        // [B,N,4]
    float* __restrict__ tembT,          // [B,N,64]
    float* __restrict__ featsT)         // [B,N,64]
{
    const int gx = blockIdx.x;
    if (gx < 2048) {
        const int a  = gx >> 10;          // 0: feats, 1: temb
        const int tt = gx & 1023;         // b * 128 + tile
        const int b  = tt >> 7;
        const int n0 = (tt & 127) << 6;
        const float* src = (a ? temb : feats) + (size_t)b * 64 * N;
        float* dst = (a ? tembT : featsT) + (size_t)b * N * 64;
        __shared__ float lds[64][65];
        const int nl = threadIdx.x & 63;
        const int c0 = threadIdx.x >> 6;   // 0..3
        #pragma unroll
        for (int i = 0; i < 16; ++i) {
            const int c = c0 + i * 4;
            lds[c][nl] = src[(size_t)c * N + n0 + nl];
        }
        __syncthreads();
        #pragma unroll
        for (int i = 0; i < 16; ++i) {
            const int n = c0 + i * 4;
            dst[(size_t)(n0 + n) * 64 + nl] = lds[nl][n];
        }
    } else {
        const int tt = gx - 2048;          // b * 32 + seg
        const int b  = tt >> 5;
        const int n  = ((tt & 31) << 8) + threadIdx.x;
        const float* pc = points + (size_t)b * 3 * N;
        float* dst = pointsT + ((size_t)b * N + n) * 4;
        const float px = pc[n];
        const float py = pc[N + n];
        const float pz = pc[2 * N + n];
        dst[0] = px;
        dst[1] = py;
        dst[2] = pz;
        dst[3] = __fadd_rn(__fadd_rn(__fmul_rn(px, px), __fmul_rn(py, py)),
                           __fmul_rn(pz, pz));   // pn^2, np op order
    }
}

// one 64-point chunk. d2 replicates np op order exactly:
// (cn + pn) - 2*cross, no fma contraction. pn^2 precomputed in vv.w.
#define PROC(vv, nn)                                                          \
    do {                                                                      \
        const float cross = __fadd_rn(                                        \
            __fadd_rn(__fmul_rn(cx, (vv).x), __fmul_rn(cy, (vv).y)),          \
            __fmul_rn(cz, (vv).z));                                           \
        const float d2 = __fsub_rn(__fadd_rn(cn, (vv).w),                     \
                                   __fmul_rn(2.0f, cross));                   \
        const bool valid = d2 < R2;                                           \
        const unsigned long long mask = __ballot(valid);                      \
        if (valid) {                                                          \
            const int slot = cnt + __builtin_amdgcn_mbcnt_hi(                 \
                (unsigned)(mask >> 32),                                       \
                __builtin_amdgcn_mbcnt_lo((unsigned)mask, 0));                \
            if (slot < K) snp[slot] = (nn);                                   \
        }                                                                     \
        cnt += (int)__popcll(mask);                                           \
    } while (0)

// ---------------------------------------------------------------------------
// Fused kernel (R3 structure + R4/R5 learnings). Block = 4 centers, 4 waves.
// Phase 0: ball query, one wave per center, 256-pt groups, ping-pong
//   prefetch, pn^2 from pointsT.w, center coords in SGPRs via readfirstlane.
// Phase 1+: gather with HALF-size LDS tile (64x65) -> 18.7 KB total ->
//   8 blocks/CU co-resident (was 4 at 35 KB): a block stalled in a long ball
//   scan is hidden behind ~7 gathering blocks on the same CU.
// ---------------------------------------------------------------------------
__global__ __launch_bounds__(256, 8) void fused_kernel(
    const float* __restrict__ pointsT,  // [B,N,4] (.w = pn^2)
    const float* __restrict__ centers,  // [B,3,M]
    const float* __restrict__ tembT,    // [B,N,64]
    const float* __restrict__ featsT,   // [B,N,64]
    float* __restrict__ out1,           // [B,3+C,M,K]
    float* __restrict__ out2)           // [B,CT,M,K]
{
    __shared__ int   sn[128];
    __shared__ float tile[64 * 65];
    __shared__ float ctile[3][128];

    const int t = threadIdx.x;
    const int MB4 = M / 4;
    const int b  = blockIdx.x / MB4;
    const int m0 = (blockIdx.x - b * MB4) * 4;
    const size_t base_mk = (size_t)m0 * K;
    const size_t cs = (size_t)M * K;

    // ---------------- phase 0: ball query, one wave per center -------------
    {
        const int wv   = t >> 6;
        const int lane = t & 63;
        const int m    = m0 + wv;
        const float cx = rfl(centers[((size_t)b * 3 + 0) * M + m]);
        const float cy = rfl(centers[((size_t)b * 3 + 1) * M + m]);
        const float cz = rfl(centers[((size_t)b * 3 + 2) * M + m]);
        const float cn = rfl(__fadd_rn(
            __fadd_rn(__fmul_rn(cx, cx), __fmul_rn(cy, cy)),
            __fmul_rn(cz, cz)));

        int* snp = &sn[wv * K];
        if (lane == 0) snp[0] = 0;      // default fill for empty ball

        const float4* pt4 = (const float4*)(pointsT + (size_t)b * N * 4);
        int cnt = 0;
        float4 va[4], vb[4];
        #pragma unroll
        for (int j = 0; j < 4; ++j) va[j] = pt4[j * 64 + lane];

        for (int g = 0; g < 32; g += 2) {
            if (g + 1 < 32) {
                #pragma unroll
                for (int j = 0; j < 4; ++j)
                    vb[j] = pt4[((g + 1) * 4 + j) * 64 + lane];
            }
            #pragma unroll
            for (int j = 0; j < 4; ++j) PROC(va[j], g * 256 + j * 64 + lane);
            if (cnt >= K || g + 1 >= 32) break;

            if (g + 2 < 32) {
                #pragma unroll
                for (int j = 0; j < 4; ++j)
                    va[j] = pt4[((g + 2) * 4 + j) * 64 + lane];
            }
            #pragma unroll
            for (int j = 0; j < 4; ++j) PROC(vb[j], (g + 1) * 256 + j * 64 + lane);
            if (cnt >= K) break;
        }

        // fill slots >= cnt with first valid index (wave-private rows)
        if (lane < K) {
            const int fill = snp[0];
            const int v    = snp[lane];
            snp[lane] = (lane < cnt) ? v : fill;
        }
    }
    __syncthreads();

    const int cq = t & 15;     // float4 slot: channels cq*4 .. cq*4+3
    const int pl = t >> 4;     // 0..15
    const float* fT = featsT + (size_t)b * N * 64;
    const float* tT = tembT  + (size_t)b * N * 64;

    // ---- phase 1: feats -> out1 channels 3..66, two half-tiles ----
    #pragma unroll
    for (int h = 0; h < 2; ++h) {
        #pragma unroll
        for (int i = 0; i < 4; ++i) {
            const int pr = i * 16 + pl;        // row in tile, 0..63
            const int n  = sn[h * 64 + pr];
            const float4 v = *(const float4*)(fT + (size_t)n * 64 + cq * 4);
            float* d = &tile[pr * 65 + cq * 4];
            d[0] = v.x; d[1] = v.y; d[2] = v.z; d[3] = v.w;
        }
        __syncthreads();
        {
            const int p   = t & 63;
            const int ch0 = t >> 6;            // 0..3
            float* o = out1 + (size_t)b * 67 * cs + 3 * cs + base_mk + h * 64 + p;
            #pragma unroll
            for (int i = 0; i < 16; ++i) {
                const int c = ch0 + i * 4;
                o[(size_t)c * cs] = tile[p * 65 + c];
            }
        }
        __syncthreads();
    }

    // ---- phase 2: temb -> out2 channels 0..63, two half-tiles ----
    #pragma unroll
    for (int h = 0; h < 2; ++h) {
        #pragma unroll
        for (int i = 0; i < 4; ++i) {
            const int pr = i * 16 + pl;
            const int n  = sn[h * 64 + pr];
            const float4 v = *(const float4*)(tT + (size_t)n * 64 + cq * 4);
            float* d = &tile[pr * 65 + cq * 4];
            d[0] = v.x; d[1] = v.y; d[2] = v.z; d[3] = v.w;
        }
        __syncthreads();
        {
            const int p   = t & 63;
            const int ch0 = t >> 6;
            float* o = out2 + (size_t)b * 64 * cs + base_mk + h * 64 + p;
            #pragma unroll
            for (int i = 0; i < 16; ++i) {
                const int c = ch0 + i * 4;
                o[(size_t)c * cs] = tile[p * 65 + c];
            }
        }
        __syncthreads();
    }

    // ---- phase 3: coords -> out1 channels 0..2 (re-centered) ----
    if (t < 128) {
        const int p = t;
        const int n = sn[p];
        const int m = m0 + (p >> 5);
        const float4 v = *(const float4*)(pointsT + ((size_t)b * N + n) * 4);
        ctile[0][p] = v.x - centers[((size_t)b * 3 + 0) * M + m];
        ctile[1][p] = v.y - centers[((size_t)b * 3 + 1) * M + m];
        ctile[2][p] = v.z - centers[((size_t)b * 3 + 2) * M + m];
    }
    __syncthreads();
    {
        const int c = t >> 7;      // 0..1
        const int p = t & 127;
        out1[((size_t)b * 67 + c) * cs + base_mk + p] = ctile[c][p];
    }
    if (t < 128) {
        out1[((size_t)b * 67 + 2) * cs + base_mk + t] = ctile[2][t];
    }
}

extern "C" void kernel_launch(void* const* d_in, const int* in_sizes, int n_in,
                              void* d_out, int out_size, void* d_ws, size_t ws_size,
                              hipStream_t stream) {
    const float* points  = (const float*)d_in[0];  // [8,3,8192]
    const float* centers = (const float*)d_in[1];  // [8,3,2048]
    const float* temb    = (const float*)d_in[2];  // [8,64,8192]
    const float* feats   = (const float*)d_in[3];  // [8,64,8192]

    // workspace layout (33 MB)
    float* pointsT = (float*)d_ws;                            // 1 MB
    float* featsT  = pointsT + (size_t)B * N * 4;             // 16 MB
    float* tembT   = featsT  + (size_t)B * N * 64;            // 16 MB

    float* out1 = (float*)d_out;                              // [8,67,2048,32]
    float* out2 = out1 + (size_t)B * (3 + C) * M * K;         // [8,64,2048,32]

    transpose_kernel<<<2304, 256, 0, stream>>>(points, temb, feats,
                                               pointsT, tembT, featsT);
    fused_kernel<<<(B * M) / 4, 256, 0, stream>>>(pointsT, centers, tembT,
                                                  featsT, out1, out2);
}

// Round 8
// 328.321 us; speedup vs baseline: 1.0768x; 1.0768x over previous
//
#include <hip/hip_runtime.h>

#define B  8
#define N  8192
#define M  2048
#define C  64
#define CT 64
#define K  32
#define R2 0.04f   // nearest f32 to 0.2*0.2, matches jnp/np promotion

__device__ __forceinline__ float rfl(float x) {
    union { float f; int i; } u;
    u.f = x;
    u.i = __builtin_amdgcn_readfirstlane(u.i);
    return u.f;
}

// ---------------------------------------------------------------------------
// Kernel 0: transpose feats/temb [B,64,N] -> [B,N,64]; points [B,3,N] ->
// [B,N,4] with .w = px^2+py^2+pz^2 (exact np op order, reused by ball query).
// Verbatim from R4/R5/R6 (passed, absmax 0.0).
// ---------------------------------------------------------------------------
__global__ __launch_bounds__(256) void transpose_kernel(
    const float* __restrict__ points,   // [B,3,N]
    const float* __restrict__ temb,     // [B,CT,N]
    const float* __restrict__ feats,    // [B,C,N]
    float* __restrict__ pointsT,        // [B,N,4]
    float* __restrict__ tembT,          // [B,N,64]
    float* __restrict__ featsT)         // [B,N,64]
{
    const int gx = blockIdx.x;
    if (gx < 2048) {
        const int a  = gx >> 10;          // 0: feats, 1: temb
        const int tt = gx & 1023;         // b * 128 + tile
        const int b  = tt >> 7;
        const int n0 = (tt & 127) << 6;
        const float* src = (a ? temb : feats) + (size_t)b * 64 * N;
        float* dst = (a ? tembT : featsT) + (size_t)b * N * 64;
        __shared__ float lds[64][65];
        const int nl = threadIdx.x & 63;
        const int c0 = threadIdx.x >> 6;   // 0..3
        #pragma unroll
        for (int i = 0; i < 16; ++i) {
            const int c = c0 + i * 4;
            lds[c][nl] = src[(size_t)c * N + n0 + nl];
        }
        __syncthreads();
        #pragma unroll
        for (int i = 0; i < 16; ++i) {
            const int n = c0 + i * 4;
            dst[(size_t)(n0 + n) * 64 + nl] = lds[nl][n];
        }
    } else {
        const int tt = gx - 2048;          // b * 32 + seg
        const int b  = tt >> 5;
        const int n  = ((tt & 31) << 8) + threadIdx.x;
        const float* pc = points + (size_t)b * 3 * N;
        float* dst = pointsT + ((size_t)b * N + n) * 4;
        const float px = pc[n];
        const float py = pc[N + n];
        const float pz = pc[2 * N + n];
        dst[0] = px;
        dst[1] = py;
        dst[2] = pz;
        dst[3] = __fadd_rn(__fadd_rn(__fmul_rn(px, px), __fmul_rn(py, py)),
                           __fmul_rn(pz, pz));   // pn^2, np op order
    }
}

// one 64-point chunk. d2 replicates np op order exactly:
// (cn + pn) - 2*cross, no fma contraction. pn^2 precomputed in vv.w.
// Verbatim from R6 (passed correctness).
#define PROC(vv, nn)                                                          \
    do {                                                                      \
        const float cross = __fadd_rn(                                        \
            __fadd_rn(__fmul_rn(cx, (vv).x), __fmul_rn(cy, (vv).y)),          \
            __fmul_rn(cz, (vv).z));                                           \
        const float d2 = __fsub_rn(__fadd_rn(cn, (vv).w),                     \
                                   __fmul_rn(2.0f, cross));                   \
        const bool valid = d2 < R2;                                           \
        const unsigned long long mask = __ballot(valid);                      \
        if (valid) {                                                          \
            const int slot = cnt + __builtin_amdgcn_mbcnt_hi(                 \
                (unsigned)(mask >> 32),                                       \
                __builtin_amdgcn_mbcnt_lo((unsigned)mask, 0));                \
            if (slot < K) snp[slot] = (nn);                                   \
        }                                                                     \
        cnt += (int)__popcll(mask);                                           \
    } while (0)

// ---------------------------------------------------------------------------
// Fused kernel = R3 structure (best passing, 328.6 us) + pn^2-in-.w + rfl.
// Block = 4 centers, 4 waves. NO min-waves launch bound (R6 lesson: the
// register cap caused spills, +24 us). Full 128x65 tile (R3's shape; R6's
// half-tile doubled barriers and regressed).
// Phase 0: ball query, one wave per center, 256-pt groups, float4 ping-pong
//   prefetch, pn^2 from pointsT.w, center coords in SGPRs via readfirstlane.
// Phase 1-3: LDS-transposed gather, fully coalesced stores.
// ---------------------------------------------------------------------------
__global__ __launch_bounds__(256) void fused_kernel(
    const float* __restrict__ pointsT,  // [B,N,4] (.w = pn^2)
    const float* __restrict__ centers,  // [B,3,M]
    const float* __restrict__ tembT,    // [B,N,64]
    const float* __restrict__ featsT,   // [B,N,64]
    float* __restrict__ out1,           // [B,3+C,M,K]
    float* __restrict__ out2)           // [B,CT,M,K]
{
    __shared__ int   sn[128];
    __shared__ float tile[128 * 65];
    __shared__ float ctile[3][128];

    const int t = threadIdx.x;
    const int MB4 = M / 4;
    const int b  = blockIdx.x / MB4;
    const int m0 = (blockIdx.x - b * MB4) * 4;
    const size_t base_mk = (size_t)m0 * K;
    const size_t cs = (size_t)M * K;

    // ---------------- phase 0: ball query, one wave per center -------------
    {
        const int wv   = t >> 6;
        const int lane = t & 63;
        const int m    = m0 + wv;
        const float cx = rfl(centers[((size_t)b * 3 + 0) * M + m]);
        const float cy = rfl(centers[((size_t)b * 3 + 1) * M + m]);
        const float cz = rfl(centers[((size_t)b * 3 + 2) * M + m]);
        const float cn = rfl(__fadd_rn(
            __fadd_rn(__fmul_rn(cx, cx), __fmul_rn(cy, cy)),
            __fmul_rn(cz, cz)));

        int* snp = &sn[wv * K];
        if (lane == 0) snp[0] = 0;      // default fill for empty ball

        const float4* pt4 = (const float4*)(pointsT + (size_t)b * N * 4);
        int cnt = 0;
        float4 va[4], vb[4];
        #pragma unroll
        for (int j = 0; j < 4; ++j) va[j] = pt4[j * 64 + lane];

        for (int g = 0; g < 32; g += 2) {
            if (g + 1 < 32) {
                #pragma unroll
                for (int j = 0; j < 4; ++j)
                    vb[j] = pt4[((g + 1) * 4 + j) * 64 + lane];
            }
            #pragma unroll
            for (int j = 0; j < 4; ++j) PROC(va[j], g * 256 + j * 64 + lane);
            if (cnt >= K || g + 1 >= 32) break;

            if (g + 2 < 32) {
                #pragma unroll
                for (int j = 0; j < 4; ++j)
                    va[j] = pt4[((g + 2) * 4 + j) * 64 + lane];
            }
            #pragma unroll
            for (int j = 0; j < 4; ++j) PROC(vb[j], (g + 1) * 256 + j * 64 + lane);
            if (cnt >= K) break;
        }

        // fill slots >= cnt with first valid index (wave-private row)
        if (lane < K) {
            const int fill = snp[0];
            const int v    = snp[lane];
            snp[lane] = (lane < cnt) ? v : fill;
        }
    }
    __syncthreads();

    const int cq = t & 15;     // float4 slot: channels cq*4 .. cq*4+3
    const int pl = t >> 4;     // 0..15
    const float* fT = featsT + (size_t)b * N * 64;
    const float* tT = tembT  + (size_t)b * N * 64;

    // ---- phase 1: feats -> out1 channels 3..66 ----
    #pragma unroll
    for (int i = 0; i < 8; ++i) {
        const int p = i * 16 + pl;
        const int n = sn[p];
        const float4 v = *(const float4*)(fT + (size_t)n * 64 + cq * 4);
        float* d = &tile[p * 65 + cq * 4];
        d[0] = v.x; d[1] = v.y; d[2] = v.z; d[3] = v.w;
    }
    __syncthreads();
    {
        const int p   = t & 127;
        const int ch0 = t >> 7;    // 0..1
        float* o = out1 + (size_t)b * 67 * cs + 3 * cs + base_mk + p;
        #pragma unroll
        for (int i = 0; i < 32; ++i) {
            const int c = ch0 + i * 2;
            o[(size_t)c * cs] = tile[p * 65 + c];
        }
    }
    __syncthreads();

    // ---- phase 2: temb -> out2 channels 0..63 ----
    #pragma unroll
    for (int i = 0; i < 8; ++i) {
        const int p = i * 16 + pl;
        const int n = sn[p];
        const float4 v = *(const float4*)(tT + (size_t)n * 64 + cq * 4);
        float* d = &tile[p * 65 + cq * 4];
        d[0] = v.x; d[1] = v.y; d[2] = v.z; d[3] = v.w;
    }
    __syncthreads();
    {
        const int p   = t & 127;
        const int ch0 = t >> 7;
        float* o = out2 + (size_t)b * 64 * cs + base_mk + p;
        #pragma unroll
        for (int i = 0; i < 32; ++i) {
            const int c = ch0 + i * 2;
            o[(size_t)c * cs] = tile[p * 65 + c];
        }
    }

    // ---- phase 3: coords -> out1 channels 0..2 (re-centered) ----
    if (t < 128) {
        const int p = t;
        const int n = sn[p];
        const int m = m0 + (p >> 5);
        const float4 v = *(const float4*)(pointsT + ((size_t)b * N + n) * 4);
        ctile[0][p] = v.x - centers[((size_t)b * 3 + 0) * M + m];
        ctile[1][p] = v.y - centers[((size_t)b * 3 + 1) * M + m];
        ctile[2][p] = v.z - centers[((size_t)b * 3 + 2) * M + m];
    }
    __syncthreads();
    {
        const int c = t >> 7;      // 0..1
        const int p = t & 127;
        out1[((size_t)b * 67 + c) * cs + base_mk + p] = ctile[c][p];
    }
    if (t < 128) {
        out1[((size_t)b * 67 + 2) * cs + base_mk + t] = ctile[2][t];
    }
}

extern "C" void kernel_launch(void* const* d_in, const int* in_sizes, int n_in,
                              void* d_out, int out_size, void* d_ws, size_t ws_size,
                              hipStream_t stream) {
    const float* points  = (const float*)d_in[0];  // [8,3,8192]
    const float* centers = (const float*)d_in[1];  // [8,3,2048]
    const float* temb    = (const float*)d_in[2];  // [8,64,8192]
    const float* feats   = (const float*)d_in[3];  // [8,64,8192]

    // workspace layout (33 MB)
    float* pointsT = (float*)d_ws;                            // 1 MB
    float* featsT  = pointsT + (size_t)B * N * 4;             // 16 MB
    float* tembT   = featsT  + (size_t)B * N * 64;            // 16 MB

    float* out1 = (float*)d_out;                              // [8,67,2048,32]
    float* out2 = out1 + (size_t)B * (3 + C) * M * K;         // [8,64,2048,32]

    transpose_kernel<<<2304, 256, 0, stream>>>(points, temb, feats,
                                               pointsT, tembT, featsT);
    fused_kernel<<<(B * M) / 4, 256, 0, stream>>>(pointsT, centers, tembT,
                                                  featsT, out1, out2);
}